// Round 1
// baseline (1834.801 us; speedup 1.0000x reference)
//
#include <hip/hip_runtime.h>

// VQC 16-wire / 10-layer statevector simulator.
//
// Bit layout of global amp index g (wire w <-> bit 15-w):
//   b15 = block half h, b14..b5 = tid (b14..b11 wave bits, b10..b5 lane bits),
//   b4..b0 = per-thread register index j (32 complex amps/thread).
// Per layer all 9 CNOTs are folded into the rotation on their TARGET wire as a
// conditional column swap of U; rotations execute in order
//   R1, R0, R15, R14, R3, R2, R5, R4, R7, R6, R9, R8, R11, R10, R13, R12
// which provably composes to the reference order. R0 (cross-block, bit15) is
// fused into the load of the next kernel launch; 10 launches ping-pong the
// state through d_ws (2 x 64 MiB) with gate coeffs (float4/gate) at +128 MiB.

#define NW 16
#define NL 10
#define NB 128

__global__ void coef_kernel(const float* __restrict__ params, float4* __restrict__ cf) {
    int idx = blockIdx.x * blockDim.x + threadIdx.x;
    if (idx >= NB * NL * NW) return;
    int wire  = idx & 15;
    int layer = (idx >> 4) % NL;
    int batch = idx / (NW * NL);
    const float* p = params + batch * (3 * NW * NL) + layer * (3 * NW) + wire * 3;
    float sx, cx, sy, cy, sz, cz;
    sincosf(0.5f * p[0], &sx, &cx);
    sincosf(0.5f * p[1], &sy, &cy);
    sincosf(0.5f * p[2], &sz, &cz);
    // U = RZ(tz) RY(ty) RX(tx);  u00 = e^{-i tz/2}(cy cx + i sy sx),
    // u01 = e^{-i tz/2}(-sy cx - i cy sx);  u10 = -conj(u01), u11 = conj(u00).
    float4 o;
    o.x =  cz * cy * cx + sz * sy * sx;   // u00.re
    o.y =  cz * sy * sx - sz * cy * cx;   // u00.im
    o.z = -cz * sy * cx - sz * cy * sx;   // u01.re
    o.w = -cz * cy * sx + sz * sy * cx;   // u01.im
    cf[idx] = o;
}

__device__ __forceinline__ float2 cmul2(float2 a, float2 b) {
    return make_float2(a.x * b.x - a.y * b.y, a.x * b.y + a.y * b.x);
}

// out_own = co*own + cp*partner  (complex)
#define ONESIDED_UPD(SR, SI, PR, PI, CO, CP)                      \
    do {                                                          \
        float _a = (SR), _b = (SI);                               \
        (SR) = CO.x * _a - CO.y * _b + CP.x * (PR) - CP.y * (PI); \
        (SI) = CO.x * _b + CO.y * _a + CP.x * (PI) + CP.y * (PR); \
    } while (0)

// two-sided register pair update: rows get coeffs (A0,A1) and (B0,B1)
#define PAIR_UPD(JA, JB, A0, A1, B0, B1)                              \
    do {                                                              \
        float ar = sr[JA], ai = si[JA], br = sr[JB], bi = si[JB];     \
        sr[JA] = A0.x * ar - A0.y * ai + A1.x * br - A1.y * bi;       \
        si[JA] = A0.x * ai + A0.y * ar + A1.x * bi + A1.y * br;       \
        sr[JB] = B0.x * ar - B0.y * ai + B1.x * br - B1.y * bi;       \
        si[JB] = B0.x * ai + B0.y * ar + B1.x * bi + B1.y * br;       \
    } while (0)

// one-sided coeff select: co = U[r][r^c], cp = U[r][(1-r)^c]
__device__ __forceinline__ void osel(float2 u00, float2 u01, float2 u10, float2 u11,
                                     int r, int cond, float2& co, float2& cp) {
    float2 a = r ? u10 : u00;  // U[r][0]
    float2 b = r ? u11 : u01;  // U[r][1]
    bool k = ((r ^ cond) & 1) != 0;
    co = k ? b : a;
    cp = k ? a : b;
}

__device__ __forceinline__ void shfl_gate(float (&sr)[32], float (&si)[32],
                                          int m, float2 co, float2 cp) {
#pragma unroll
    for (int j = 0; j < 32; ++j) {
        float pr = __shfl_xor(sr[j], m, 64);
        float pi = __shfl_xor(si[j], m, 64);
        ONESIDED_UPD(sr[j], si[j], pr, pi, co, cp);
    }
}

__device__ __forceinline__ void lds_gate(float (&sr)[32], float (&si)[32],
                                         float* ldsr, float* ldsi,
                                         int tid, int pmask, float2 co, float2 cp) {
#pragma unroll
    for (int half_ = 0; half_ < 2; ++half_) {
        const int jb = half_ * 16;
        __syncthreads();
#pragma unroll
        for (int q = 0; q < 16; ++q) {
            ldsr[tid * 17 + q] = sr[jb + q];
            ldsi[tid * 17 + q] = si[jb + q];
        }
        __syncthreads();
        const int p = (tid ^ pmask) * 17;
#pragma unroll
        for (int q = 0; q < 16; ++q) {
            float pr = ldsr[p + q], pi = ldsi[p + q];
            ONESIDED_UPD(sr[jb + q], si[jb + q], pr, pi, co, cp);
        }
    }
}

// MODE 0: layer-0 product state + R1(L1), store.
// MODE 1: load+R0(L), rest of layer L, R1(L+1), store.
// MODE 2: load+R0(L), rest of layer L, probs -> out.
template <int MODE>
__global__ __launch_bounds__(1024) void vqc_step(const float4* __restrict__ cf,
                                                 const float2* __restrict__ src,
                                                 float2* __restrict__ dst,
                                                 float* __restrict__ out, int L) {
    __shared__ float ldsr[1024 * 17];
    __shared__ float ldsi[1024 * 17];
    const int bb  = blockIdx.x >> 1;
    const int h   = blockIdx.x & 1;
    const int tid = threadIdx.x;
    const int cbase = bb * NL * NW;

    float sr[32], si[32];

#define LOADU(LAY, WIRE)                            \
    float2 u00, u01, u10, u11;                      \
    {                                               \
        float4 c = cf[cbase + (LAY) * NW + (WIRE)]; \
        u00 = make_float2(c.x, c.y);                \
        u01 = make_float2(c.z, c.w);                \
        u10 = make_float2(-c.z, c.w);               \
        u11 = make_float2(c.x, -c.y);               \
    }

    if (MODE == 0) {
        // ---- layer 0: CNOTs are identity on |0>, state = product of U[:,0] ----
        float2 P = make_float2(1.f, 0.f);
#pragma unroll
        for (int w = 0; w <= 10; ++w) {
            LOADU(0, w);
            int bit = (w == 0) ? h : ((tid >> (10 - w)) & 1);
            float2 f = bit ? u10 : u00;
            P = cmul2(P, f);
        }
        float2 f0[5], f1[5];
#pragma unroll
        for (int w = 11; w <= 15; ++w) {
            LOADU(0, w);
            f0[w - 11] = u00;
            f1[w - 11] = u10;
        }
#pragma unroll
        for (int j = 0; j < 32; ++j) {
            float2 a = P;
            a = cmul2(a, ((j >> 4) & 1) ? f1[0] : f0[0]);
            a = cmul2(a, ((j >> 3) & 1) ? f1[1] : f0[1]);
            a = cmul2(a, ((j >> 2) & 1) ? f1[2] : f0[2]);
            a = cmul2(a, ((j >> 1) & 1) ? f1[3] : f0[3]);
            a = cmul2(a, ((j >> 0) & 1) ? f1[4] : f0[4]);
            sr[j] = a.x;
            si[j] = a.y;
        }
    } else {
        // ---- load + R0(L) with CN(15,0) folded (cond = j0^j1 on pre-CNOT bits) ----
        LOADU(L, 0);
        float2 co = h ? u11 : u00;  // U[h][h]
        float2 cp = h ? u10 : u01;  // U[h][1-h]
        const float2* s0 = src + (((size_t)bb << 16) | (size_t)tid);
#pragma unroll
        for (int j = 0; j < 32; ++j) {
            float2 a0 = s0[(size_t)j << 11];
            float2 a1 = s0[((size_t)j << 11) | (1 << 10)];
            float2 own = h ? a1 : a0;
            float2 par = h ? a0 : a1;
            const bool c = ((j ^ (j >> 1)) & 1) != 0;
            float2 x = c ? cp : co;
            float2 y = c ? co : cp;
            sr[j] = x.x * own.x - x.y * own.y + y.x * par.x - y.y * par.y;
            si[j] = x.x * own.y + x.y * own.x + y.x * par.y + y.y * par.x;
        }
    }

    if (MODE != 0) {
        // ---- R15: reg bit0, cond = bit1 (CN(14,15) fold) ----
        {
            LOADU(L, 15);
#pragma unroll
            for (int jp = 0; jp < 16; ++jp) {
                const int jA = jp * 2, jB = jA + 1;
                const bool c = (jp & 1) != 0;
                float2 a0 = c ? u01 : u00, a1 = c ? u00 : u01;
                float2 b0 = c ? u11 : u10, b1 = c ? u10 : u11;
                PAIR_UPD(jA, jB, a0, a1, b0, b1);
            }
        }
        // ---- R14: reg bit1 ----
        {
            LOADU(L, 14);
#pragma unroll
            for (int jp = 0; jp < 16; ++jp) {
                const int jA = ((jp >> 1) << 2) | (jp & 1), jB = jA | 2;
                PAIR_UPD(jA, jB, u00, u01, u10, u11);
            }
        }
        // ---- R3: LDS m=128 (b12), r=tid[7], cond=tid[8] (CN(2,3) fold) ----
        {
            LOADU(L, 3);
            float2 co, cp;
            osel(u00, u01, u10, u11, (tid >> 7) & 1, (tid >> 8) & 1, co, cp);
            lds_gate(sr, si, ldsr, ldsi, tid, 128, co, cp);
        }
        // ---- R2: LDS m=256 (b13), r=tid[8] ----
        {
            LOADU(L, 2);
            float2 co, cp;
            osel(u00, u01, u10, u11, (tid >> 8) & 1, 0, co, cp);
            lds_gate(sr, si, ldsr, ldsi, tid, 256, co, cp);
        }
        // ---- R5: shfl m=32 (b10), r=tid[5], cond=tid[6] (CN(4,5) fold) ----
        {
            LOADU(L, 5);
            float2 co, cp;
            osel(u00, u01, u10, u11, (tid >> 5) & 1, (tid >> 6) & 1, co, cp);
            shfl_gate(sr, si, 32, co, cp);
        }
        // ---- R4: LDS m=64 (b11), r=tid[6] ----
        {
            LOADU(L, 4);
            float2 co, cp;
            osel(u00, u01, u10, u11, (tid >> 6) & 1, 0, co, cp);
            lds_gate(sr, si, ldsr, ldsi, tid, 64, co, cp);
        }
        // ---- R7: shfl m=8 (b8), r=tid[3], cond=tid[4] (CN(6,7) fold) ----
        {
            LOADU(L, 7);
            float2 co, cp;
            osel(u00, u01, u10, u11, (tid >> 3) & 1, (tid >> 4) & 1, co, cp);
            shfl_gate(sr, si, 8, co, cp);
        }
        // ---- R6: shfl m=16 (b9), r=tid[4] ----
        {
            LOADU(L, 6);
            float2 co, cp;
            osel(u00, u01, u10, u11, (tid >> 4) & 1, 0, co, cp);
            shfl_gate(sr, si, 16, co, cp);
        }
        // ---- R9: shfl m=2 (b6), r=tid[1], cond=tid[2] (CN(8,9) fold) ----
        {
            LOADU(L, 9);
            float2 co, cp;
            osel(u00, u01, u10, u11, (tid >> 1) & 1, (tid >> 2) & 1, co, cp);
            shfl_gate(sr, si, 2, co, cp);
        }
        // ---- R8: shfl m=4 (b7), r=tid[2] ----
        {
            LOADU(L, 8);
            float2 co, cp;
            osel(u00, u01, u10, u11, (tid >> 2) & 1, 0, co, cp);
            shfl_gate(sr, si, 4, co, cp);
        }
        // ---- R11: reg bit4, cond = lane bit0 (CN(10,11) fold, runtime select) ----
        {
            LOADU(L, 11);
            const bool c = (tid & 1) != 0;
            float2 a0 = c ? u01 : u00, a1 = c ? u00 : u01;
            float2 b0 = c ? u11 : u10, b1 = c ? u10 : u11;
#pragma unroll
            for (int jp = 0; jp < 16; ++jp) PAIR_UPD(jp, jp + 16, a0, a1, b0, b1);
        }
        // ---- R10: shfl m=1 (b5), r=tid[0] ----
        {
            LOADU(L, 10);
            float2 co, cp;
            osel(u00, u01, u10, u11, tid & 1, 0, co, cp);
            shfl_gate(sr, si, 1, co, cp);
        }
        // ---- R13: reg bit2, cond = bit3 (CN(12,13) fold) ----
        {
            LOADU(L, 13);
#pragma unroll
            for (int jp = 0; jp < 16; ++jp) {
                const int jA = ((jp >> 2) << 3) | (jp & 3), jB = jA | 4;
                const bool c = ((jp >> 2) & 1) != 0;
                float2 a0 = c ? u01 : u00, a1 = c ? u00 : u01;
                float2 b0 = c ? u11 : u10, b1 = c ? u10 : u11;
                PAIR_UPD(jA, jB, a0, a1, b0, b1);
            }
        }
        // ---- R12: reg bit3 ----
        {
            LOADU(L, 12);
#pragma unroll
            for (int jp = 0; jp < 16; ++jp) {
                const int jA = ((jp >> 3) << 4) | (jp & 7), jB = jA | 8;
                PAIR_UPD(jA, jB, u00, u01, u10, u11);
            }
        }
    }

    if (MODE != 2) {
        // ---- R1(L+1): LDS m=512 (b14), r=tid[9], cond=h (CN(0,1) fold) ----
        {
            LOADU(L + 1, 1);
            float2 co, cp;
            osel(u00, u01, u10, u11, (tid >> 9) & 1, h, co, cp);
            lds_gate(sr, si, ldsr, ldsi, tid, 512, co, cp);
        }
        float2* d = dst + (((size_t)bb << 16) | (size_t)(h << 10) | (size_t)tid);
#pragma unroll
        for (int j = 0; j < 32; ++j) d[(size_t)j << 11] = make_float2(sr[j], si[j]);
    } else {
        float* o = out + (((size_t)bb << 16) | (size_t)(h << 15) | (size_t)(tid << 5));
        float4* o4 = (float4*)o;
#pragma unroll
        for (int k = 0; k < 8; ++k) {
            float4 v;
            v.x = sr[4 * k + 0] * sr[4 * k + 0] + si[4 * k + 0] * si[4 * k + 0];
            v.y = sr[4 * k + 1] * sr[4 * k + 1] + si[4 * k + 1] * si[4 * k + 1];
            v.z = sr[4 * k + 2] * sr[4 * k + 2] + si[4 * k + 2] * si[4 * k + 2];
            v.w = sr[4 * k + 3] * sr[4 * k + 3] + si[4 * k + 3] * si[4 * k + 3];
            o4[k] = v;
        }
    }
#undef LOADU
}

extern "C" void kernel_launch(void* const* d_in, const int* in_sizes, int n_in,
                              void* d_out, int out_size, void* d_ws, size_t ws_size,
                              hipStream_t stream) {
    const float* params = (const float*)d_in[0];
    float* out = (float*)d_out;
    char* w = (char*)d_ws;
    float2* buf0 = (float2*)w;                       // 64 MiB
    float2* buf1 = (float2*)(w + (1ULL << 26));      // 64 MiB
    float4* cf   = (float4*)(w + (1ULL << 27));      // 320 KiB gate coeffs

    coef_kernel<<<80, 256, 0, stream>>>(params, cf);

    vqc_step<0><<<256, 1024, 0, stream>>>(cf, nullptr, buf0, nullptr, 0);
    for (int L = 1; L <= 8; ++L) {
        float2* s = (L & 1) ? buf0 : buf1;
        float2* d = (L & 1) ? buf1 : buf0;
        vqc_step<1><<<256, 1024, 0, stream>>>(cf, s, d, nullptr, L);
    }
    vqc_step<2><<<256, 1024, 0, stream>>>(cf, buf0, nullptr, out, 9);
}